// Round 5
// baseline (38.892 us; speedup 1.0000x reference)
//
#include <hip/hip_runtime.h>

#define NEGF   (-1e30f)
#define T_DIM  128
#define U_DIM  64
#define U1     65
#define V_DIM  1024
#define B_DIM  8
#define DMAX   192   // T + U1 - 1
#define L2E    1.4426950408889634f
#define LN2    0.6931471805599453f

// Native single-instruction transcendentals (v_exp_f32 = 2^x, v_log_f32 = log2 x).
__device__ __forceinline__ float fexp2(float x) {
    float r; asm("v_exp_f32 %0, %1" : "=v"(r) : "v"(x)); return r;
}
__device__ __forceinline__ float flog2(float x) {
    float r; asm("v_log_f32 %0, %1" : "=v"(r) : "v"(x)); return r;
}

// Kernel 1: logsumexp rows, 2 rows per wave paired on t: (b,t0,u) and
// (b,t0+1,u). Halves wave/block count vs 1-row-per-wave (33,280 waves, 8,320
// blocks) to cut per-wave overhead; per-row compute and store paths are
// bit-identical to the verified R4 kernel. Emits log2-domain values into the
// interleaved, label-pre-shifted diagonal layout:
//   pair[b][t+u][u  ].x = blank2(t,u) = (pred[0]   - lse)*log2(e)
//   pair[b][t+u][u+1].y = label2(t,u) = (pred[tgt] - lse)*log2(e)   (u < U)
// Rows with t >= pred_len[b] or u > target_len[b] are never consumed by the
// alpha recurrence, so they are skipped. Also zeroes out[0].
__global__ __launch_bounds__(256) void lse_kernel(
    const float* __restrict__ pred, const int* __restrict__ target,
    const int* __restrict__ pred_len, const int* __restrict__ target_len,
    float* __restrict__ pairF, float* __restrict__ out)
{
    if (blockIdx.x == 0 && threadIdx.x == 0) out[0] = 0.0f;

    const int wave = blockIdx.x * 4 + (threadIdx.x >> 6);
    const int lane = threadIdx.x & 63;
    const int WPB  = (T_DIM / 2) * U1;            // 4160 waves per batch
    const int b    = wave / WPB;
    const int rem  = wave - b * WPB;
    const int tp   = rem / U1;
    const int u    = rem - tp * U1;
    const int t0   = tp * 2;

    const int tl = pred_len[b], uq = target_len[b];
    if (t0 >= tl || u > uq) return;              // wave-uniform exit
    const bool has1 = (t0 + 1 < tl);             // wave-uniform

    const float*  row0 = pred + ((size_t)(b * T_DIM + t0) * U1 + u) * V_DIM;
    const float4* r40  = (const float4*)row0;
    const float4* r41  = (const float4*)(row0 + (size_t)U1 * V_DIM);

    float4 a0 = r40[lane];
    float4 a1 = r40[lane + 64];
    float4 a2 = r40[lane + 128];
    float4 a3 = r40[lane + 192];
    float4 c0, c1, c2, c3;
    if (has1) {
        c0 = r41[lane];
        c1 = r41[lane + 64];
        c2 = r41[lane + 128];
        c3 = r41[lane + 192];
    }

    // Same per-row summation order as the verified kernel (bit-stable).
    float s0 = __expf(a0.x) + __expf(a0.y) + __expf(a0.z) + __expf(a0.w)
             + __expf(a1.x) + __expf(a1.y) + __expf(a1.z) + __expf(a1.w)
             + __expf(a2.x) + __expf(a2.y) + __expf(a2.z) + __expf(a2.w)
             + __expf(a3.x) + __expf(a3.y) + __expf(a3.z) + __expf(a3.w);
    #pragma unroll
    for (int off = 32; off; off >>= 1) s0 += __shfl_xor(s0, off);
    const float l2s0 = flog2(s0);

    float l2s1 = 0.0f;
    if (has1) {
        float s1 = __expf(c0.x) + __expf(c0.y) + __expf(c0.z) + __expf(c0.w)
                 + __expf(c1.x) + __expf(c1.y) + __expf(c1.z) + __expf(c1.w)
                 + __expf(c2.x) + __expf(c2.y) + __expf(c2.z) + __expf(c2.w)
                 + __expf(c3.x) + __expf(c3.y) + __expf(c3.z) + __expf(c3.w);
        #pragma unroll
        for (int off = 32; off; off >>= 1) s1 += __shfl_xor(s1, off);
        l2s1 = flog2(s1);
    }

    // Label logits from registers (bit-identical to reloading row[tg]).
    float labv0 = 0.0f, labv1 = 0.0f;
    if (u < U_DIM) {                             // wave-uniform branch
        const int tg = target[b * U_DIM + u];    // 1..1023 (never blank)
        const int g = tg >> 8, c = tg & 3, sl = (tg >> 2) & 63;
        float4 ag  = (g == 0) ? a0 : (g == 1) ? a1 : (g == 2) ? a2 : a3;
        float  cm0 = (c == 0) ? ag.x : (c == 1) ? ag.y : (c == 2) ? ag.z : ag.w;
        labv0 = __shfl(cm0, sl);
        if (has1) {
            float4 cg  = (g == 0) ? c0 : (g == 1) ? c1 : (g == 2) ? c2 : c3;
            float  cm1 = (c == 0) ? cg.x : (c == 1) ? cg.y
                       : (c == 2) ? cg.z : cg.w;
            labv1 = __shfl(cm1, sl);
        }
    }

    if (lane == 0) {
        const int base0 = (b * DMAX + t0 + u) * U1;      // diagonal d = t0+u
        pairF[2 * (base0 + u)] = a0.x * L2E - l2s0;      // .x: blank2[t0,u]
        if (u < U_DIM)
            pairF[2 * (base0 + u + 1) + 1] = labv0 * L2E - l2s0;
        if (has1) {
            const int base1 = base0 + U1;                // diagonal d = t0+u+1
            pairF[2 * (base1 + u)] = c0.x * L2E - l2s1;  // .x: blank2[t0+1,u]
            if (u < U_DIM)
                pairF[2 * (base1 + u + 1) + 1] = labv1 * L2E - l2s1;
        }
    }
}

// Alpha recurrence body, log2 domain, reading the LDS-resident trellis.
// Lane u owns column u. W64 = (target_len == 64): only then is the u=64
// column chain (a64) needed. PF=8 named slots cover ds_read latency.
// Branchless steps; trellis edges encoded as NEGF masks at load time.
// R5 delta: graduated vmcnt ladder. vmcnt retires oldest-first; with
// niter >= 49 (d_end >= 95), s_waitcnt vmcnt(K) guarantees >= 49-K staging
// iterations done = float2 indices [0,(49-K)*128) resident:
//   K=40 -> rows 0..16 | 32 -> ..32 | 24 -> ..48 | 16 -> ..63 | 8 -> ..79
// Each phase only runs groups whose prefetch reach (db+14) is covered.
template<bool W64>
__device__ __forceinline__ float alpha_body(
    const float2* smem, const int u, const int d_end, const int uq)
{
    float cur = (u == 0) ? 0.0f : NEGF;   // diagonal 0: alpha[0,0] = 0
    float a64 = NEGF;                     // column u=64 state (W64 only)

#define SLOT_DECL(K) float bl##K, lam##K, bl64##K, l63##K;
    SLOT_DECL(0) SLOT_DECL(1) SLOT_DECL(2) SLOT_DECL(3)
    SLOT_DECL(4) SLOT_DECL(5) SLOT_DECL(6) SLOT_DECL(7)

    // load diagonal row r into named slot K from LDS; rows clamped to d_end
    // (clamped slots are never consumed). Masks encode trellis edges:
    //  bl : vertical pred needs t-1>=0 <=> u <= rr
    //  lam: horizontal pred needs 1 <= u <= rr+1 (unsigned trick)
    //  bl64/l63: u=64 column needs rr>=64 / rr>=63 (wave-uniform)
#define LOAD_SLOT(K, r) { \
        int rr = (r); if (rr > d_end) rr = d_end; \
        float2 a = smem[rr * U1 + u]; \
        bl##K  = (u <= rr) ? a.x : NEGF; \
        lam##K = ((unsigned)(u - 1) <= (unsigned)rr) ? a.y : NEGF; \
        if (W64) { \
            float2 qq = smem[rr * U1 + U_DIM]; \
            bl64##K = (rr >= U_DIM) ? qq.x : NEGF; \
            l63##K  = (rr >= 63)    ? qq.y : NEGF; \
        } else { bl64##K = NEGF; l63##K = NEGF; } \
    }

    // consume slot K (holding row d-1) to advance one diagonal. Branchless.
#define STEP(K) { \
        float h_pre = __int_as_float(__builtin_amdgcn_update_dpp( \
            0, __float_as_int(cur), 0x138 /*wave_shr1*/, 0xf, 0xf, true)); \
        float a63_ = W64 ? __int_as_float( \
            __builtin_amdgcn_readlane(__float_as_int(cur), 63)) : 0.0f; \
        float v = cur + bl##K; \
        float h = h_pre + lam##K; \
        float m = fmaxf(v, h); \
        cur = m + flog2(1.0f + fexp2(-fabsf(v - h))); \
        if (W64) { \
            float v2 = a64 + bl64##K; \
            float h2 = a63_ + l63##K; \
            float m2 = fmaxf(v2, h2); \
            a64 = m2 + flog2(1.0f + fexp2(-fabsf(v2 - h2))); \
        } \
    }

#define GROUP8 { \
        STEP(0) LOAD_SLOT(0, db + 7)  \
        STEP(1) LOAD_SLOT(1, db + 8)  \
        STEP(2) LOAD_SLOT(2, db + 9)  \
        STEP(3) LOAD_SLOT(3, db + 10) \
        STEP(4) LOAD_SLOT(4, db + 11) \
        STEP(5) LOAD_SLOT(5, db + 12) \
        STEP(6) LOAD_SLOT(6, db + 13) \
        STEP(7) LOAD_SLOT(7, db + 14) }

#define WAITV(N) asm volatile("s_waitcnt vmcnt(" #N ")" ::: "memory");

    // rows 0..16 resident: initial slots (rows 0..7) + first group (reach 15)
    WAITV(40)
    LOAD_SLOT(0, 0) LOAD_SLOT(1, 1) LOAD_SLOT(2, 2) LOAD_SLOT(3, 3)
    LOAD_SLOT(4, 4) LOAD_SLOT(5, 5) LOAD_SLOT(6, 6) LOAD_SLOT(7, 7)

    int db = 1;                                   // db ≡ 1 (mod 8) always
    for (; db + 7 <= d_end && db <= 1;  db += 8) GROUP8   // reach <= 15
    WAITV(32)                                             // rows ..32
    for (; db + 7 <= d_end && db <= 17; db += 8) GROUP8   // reach <= 31
    WAITV(24)                                             // rows ..48
    for (; db + 7 <= d_end && db <= 33; db += 8) GROUP8   // reach <= 47
    WAITV(16)                                             // rows ..63
    for (; db + 7 <= d_end && db <= 49; db += 8) GROUP8   // reach <= 63
    WAITV(8)                                              // rows ..79
    for (; db + 7 <= d_end && db <= 65; db += 8) GROUP8   // reach <= 79
    WAITV(0)                                              // all rows
    for (; db + 7 <= d_end; db += 8) GROUP8

    // tail: at most 7 remaining diagonals; slots 0..6 already hold their rows
    if (db + 0 <= d_end) STEP(0)
    if (db + 1 <= d_end) STEP(1)
    if (db + 2 <= d_end) STEP(2)
    if (db + 3 <= d_end) STEP(3)
    if (db + 4 <= d_end) STEP(4)
    if (db + 5 <= d_end) STEP(5)
    if (db + 6 <= d_end) STEP(6)

#undef WAITV
#undef GROUP8
#undef STEP
#undef LOAD_SLOT
#undef SLOT_DECL

    // ll = (alpha2[tl-1, uq] + blank2[tl-1, uq]) * ln2
    float val = W64 ? a64 : __shfl(cur, uq);
    float fb  = smem[d_end * U1 + uq].x;         // blank2[tl-1, uq], written
    return (val + fb) * LN2;
}

// One block (64 threads = 1 wave) per batch element, each on its own CU.
// Stage the whole per-batch trellis (<= 99,840 B) into LDS asynchronously;
// the recurrence starts once the first 17 rows are resident (vmcnt(40)) and
// ratchets down the outstanding-load budget as it advances.
__global__ __launch_bounds__(64) void alpha_kernel(
    const float* __restrict__ pairF,
    const int* __restrict__ pred_len, const int* __restrict__ target_len,
    float* __restrict__ out)
{
    __shared__ __align__(16) float2 smem[DMAX * U1 + 64];   // +pad for over-copy

    const int b  = blockIdx.x;
    const int u  = threadIdx.x;        // 0..63
    const int tl = pred_len[b];
    const int uq = target_len[b];
    const int d_end = tl - 1 + uq;     // final diagonal needed (>= 95 always)

    const float* srcF = pairF + (size_t)b * (2 * DMAX * U1);

    // rows 0..d_end = (d_end+1)*65 float2; 128 float2 (1 KB) per iteration.
    const int niter = ((d_end + 1) * U1 + 127) >> 7;        // 49..98
    for (int i = 0; i < niter; ++i) {
        const float* g = srcF + (size_t)i * 256 + u * 4;    // per-lane 16 B
        __builtin_amdgcn_global_load_lds(
            (const __attribute__((address_space(1))) void*)g,
            (__attribute__((address_space(3))) void*)(&smem[i * 128]),
            16, 0, 0);
    }
    // graduated vmcnt waits happen inside alpha_body

    float ll = (uq == U_DIM) ? alpha_body<true >(smem, u, d_end, uq)
                             : alpha_body<false>(smem, u, d_end, uq);

    if (u == 0) atomicAdd(out, -ll * (1.0f / B_DIM));
}

extern "C" void kernel_launch(void* const* d_in, const int* in_sizes, int n_in,
                              void* d_out, int out_size, void* d_ws, size_t ws_size,
                              hipStream_t stream) {
    const float* pred       = (const float*)d_in[0];
    const int*   target     = (const int*)d_in[1];
    const int*   pred_len   = (const int*)d_in[2];
    const int*   target_len = (const int*)d_in[3];
    float* out = (float*)d_out;

    float* pairF = (float*)d_ws;                   // 2*B*DMAX*U1 floats ≈ 800 KB

    const int nwaves = B_DIM * (T_DIM / 2) * U1;   // 33280 waves, 2 rows each
    lse_kernel<<<nwaves / 4, 256, 0, stream>>>(pred, target, pred_len,
                                               target_len, pairF, out);
    alpha_kernel<<<B_DIM, 64, 0, stream>>>(pairF, pred_len, target_len, out);
}